// Round 6
// baseline (280.748 us; speedup 1.0000x reference)
//
#include <hip/hip_runtime.h>

// CTC batch cost, linear-domain, single wave per batch element, DIAGONAL SKEW.
// Lane L owns states 4L..4L+3 (S=201); at wave-step n it computes t = n-L.
// ROUND 6: DS-op diet. r0-r5 data: residual stall per step tracks DS-op
// count (~35-40cy/op for a solo wave) independent of scheduling slack
// (r1 prefetch neutral, r2 indexed-slack neutral, r5 batching doubled it).
// So: remove DS ops. The 3 random-class ds_read_b32 + ds_write_b64 + global
// reload are replaced by a per-lane packed pipeline:
//   step n: each lane global-loads ITS OWN (blank,y0,y1) of row min(n+16,1023)
//     -> all 64 lanes hit the SAME 512B row (<=9 line transactions, SGPR
//     base + per-lane class offset) -> QG[16] reg queue (12-step vmcnt slack
//     ~1300cy > 900cy HBM latency).
//   step n: ds_write_b128 the packed float4 loaded 12 steps ago (row
//     min(n+4,1023)) into pbuf[(n+4)&127][lane]  ([slot][lane][16B] layout,
//     GEMM-standard, conflict-free).
//   step n: ONE ds_read_b128 pbuf[(n+4-lane)&127][lane] -> PQ[4] (consumed
//     at n+4; 4-step lgkm slack, lgkmcnt(13) encodable).
//   halo: indexed HQ[16] ring (no reg rotation), 2-step slack as r4.
// DS/step: 1 write_b128 + 1 read_b128 + 1.25 bpermute = 3.25 wide,
// conflict-free ops (was 4.25 with 3 random-bank b32 gathers).
//
// Slot/row timing (verified): slot s holds row min(s,1023) once written at
// step s-4 (mod 128); consumer read for step n' targets slot (n'-lane)&127,
// issued at n'-4 >= write step n'-lane-4 (same-step for lane 0: write
// precedes read in body order; single wave => DS program-ordered). Dormant
// lanes (t<0) read wrapped slots 64..127: pre-zeroed, and their first
// overwrite (step >= 124) is after the last wrapped read (step <= 67) only
// for slots whose zero value was already consumed -> exact 0 contributions.
// Ghost lanes 51..63 compute on clamped labels; data flows only rightward
// (shfl_up), never into real lanes; epilogue reads lanes < 51 only.
//
// Exactness: identical recurrence/renorm/epoch scheme as r4 (absmax 0.0);
// all consumed (value, exponent) pairs unchanged -> absmax 0.0 expected.
//
// Recurrence: n0=(a0+h1)*pb; n1=(a1+a0+ms1*h1)*p0; n2=(a2+a1)*pb;
//             n3=(a3+a2+ms3*a1)*p1; per-lane e, renorm every 4 steps.

#define Bc 256
#define Tc 1024
#define Cc 128
#define Uc 100
#define BLANKc 127
#define EPSc 1e-7f
#define LN2f 0.69314718055994530942f
#define SLOTS 128            // pbuf ring depth (live span 71)
#define QGD 16               // global->reg queue depth (12-step lag)

__global__ __launch_bounds__(64) void ctc_vg_kernel(
    const float* __restrict__ y_pred,     // [B,T,C] post-softmax probs
    const int*   __restrict__ y_true,     // [B,U]
    const int*   __restrict__ label_len,  // [B]
    float*       __restrict__ out)        // [B,1]
{
    __shared__ float4 pbuf[SLOTS][64];    // 128 KB: per-lane (pb,p0,p1,-)
    __shared__ float  shA[204];
    __shared__ int    shE[64];

    const int b    = blockIdx.x;
    const int lane = threadIdx.x;                  // 0..63
    const float* gp = y_pred + (size_t)b * (Tc * Cc);

    // ---- per-lane label classes & skip masks (time-invariant) ----
    const int k0  = 2*lane, k1 = 2*lane+1;
    const int k0c = k0 < Uc ? k0 : Uc-1;
    const int k1c = k1 < Uc ? k1 : Uc-1;
    const int y0  = y_true[b*Uc + k0c];            // class of state 4L+1
    const int y1  = y_true[b*Uc + k1c];            // class of state 4L+3
    int ym1 = y0;
    if (lane > 0) ym1 = y_true[b*Uc + k0 - 1];
    const float ms1 = (lane > 0 && y0 != ym1) ? 1.0f : 0.0f;
    const float ms3 = (y1 != y0) ? 1.0f : 0.0f;
    const float mh  = (lane > 0) ? 1.0f : 0.0f;    // lane 0 has no left halo

    // ---- t=0 init (only lane 0 holds mass) ----
    float a0=0.f, a1=0.f, a2=0.f, a3=0.f;
    if (lane == 0) { a0 = gp[BLANKc]+EPSc; a1 = gp[y0]+EPSc; }
    int e = 0;

    // ---- zero wrapped-read slots 64..127 (dormant reads -> exact 0) ----
    const float4 z4 = make_float4(0.f,0.f,0.f,0.f);
    for (int s = 64; s < SLOTS; ++s) pbuf[s][lane] = z4;

    // ---- stage rows 0..4 directly ----
    for (int r = 0; r < 5; ++r) {
        const float* rp = gp + r*Cc;
        pbuf[r][lane] = make_float4(rp[BLANKc], rp[y0], rp[y1], 0.f);
    }
    // ---- QG: rows 5..16 -> QG[r&15] (consumed at steps 1..12) ----
    float4 QG[QGD];
#pragma unroll
    for (int k = 0; k < QGD; ++k) QG[k] = z4;
    for (int r = 5; r <= 16; ++r) {
        const float* rp = gp + r*Cc;
        QG[r & 15] = make_float4(rp[BLANKc], rp[y0], rp[y1], 0.f);
    }
    // ---- PQ pre-issue for steps 1..4 ----
    float4 PQ[4];
#pragma unroll
    for (int nc = 1; nc <= 4; ++nc)
        PQ[nc & 3] = pbuf[(nc - lane) & (SLOTS-1)][lane];

    // ---- halo ring (indexed, no rotation) + epoch pipes ----
    float HQ[16];
#pragma unroll
    for (int k = 0; k < 16; ++k) HQ[k] = 0.f;
    int ELa = 0, ELb = 0;

    auto body = [&](int n, int j, bool fzp) {
        // 1) stage: ds_write row min(n+4,1023) (loaded 12 steps ago)
        pbuf[(n + 4) & (SLOTS-1)][lane] = QG[(j + 5) & 15];
        // 2) refill QG with row min(n+16,1023): 3 same-row scattered loads
        {
            int rv = n + 16; rv = rv > Tc-1 ? Tc-1 : rv;   // uniform (SALU)
            const float* rp = gp + rv * Cc;
            QG[(j + 1) & 15] = make_float4(rp[BLANKc], rp[y0], rp[y1], 0.f);
        }
        // 3) consume this step's probs (LDS read issued 4 steps ago)
        const float4 pv = PQ[(j + 1) & 3];
        const float pb = pv.x + EPSc, p0 = pv.y + EPSc, p1 = pv.z + EPSc;
        // 4) re-issue PQ read for step n+4 (slot written in (1) this step)
        PQ[(j + 1) & 3] = pbuf[(n + 4 - lane) & (SLOTS-1)][lane];
        // 5) epoch select (compile-time by j) + halo from left's step n-2
        const int el = ((j == 0) || (j >= 5 && j <= 8) || (j >= 13)) ? ELb : ELa;
        const float h1r = HQ[(j + 14) & 15];
        int d = el - e; d = d > 126 ? 126 : d;
        const float h1 = mh * ldexpf(h1r, d);
        const float n0 = (a0 + h1) * pb;
        const float n1 = (a1 + a0 + ms1*h1) * p0;
        const float nv = (a2 + a1) * pb;
        const float n3 = (a3 + a2 + ms3*a1) * p1;
        bool upd = true;
        if (fzp) upd = (lane >= n - (Tc-1));       // freeze lanes past t=1023
        if (upd) { a0=n0; a1=n1; a2=nv; a3=n3; }
        if ((j & 3) == 3) {                        // renorm (pow2-exact)
            const float m = fmaxf(fmaxf(a0,a1), fmaxf(a2,a3));
            int ex = (int)((__float_as_uint(m) >> 23) & 0xFF) - 127;
            ex = (m > 0.0f) ? ex : (el - e);       // dormant: adopt left epoch
            a0 = ldexpf(a0,-ex); a1 = ldexpf(a1,-ex);
            a2 = ldexpf(a2,-ex); a3 = ldexpf(a3,-ex);
            e += ex;
        }
        // halo out: a3 every step (post-renorm on renorm steps), e per epoch
        HQ[j] = __shfl_up(a3, 1, 64);
        if ((j & 3) == 3) {
            const int es = __shfl_up(e, 1, 64);
            if (j == 3 || j == 11) ELb = es; else ELa = es;
        }
    };

    // ---- wave-steps n = 1..1073 (lane 50 ends t=1023 at n=1073) ----
    int n = 1;
    for (int c = 0; c < 63; ++c) {                 // n = 1..1008: no freeze
#pragma unroll
        for (int j = 0; j < 16; ++j) { body(n, j, false); ++n; }
    }
    for (int c = 0; c < 4; ++c) {                  // n = 1009..1072 (freeze
#pragma unroll                                     //  predicate inert <1024)
        for (int j = 0; j < 16; ++j) { body(n, j, true); ++n; }
    }
    body(n, 0, true);                              // n = 1073 (1073&15 == 1)

    // ---- epilogue: loss = -ln( A[2L-1] + A[2L] ), A = a * 2^e ----
    if (lane < 51) {
        shA[4*lane+0] = a0; shA[4*lane+1] = a1;
        shA[4*lane+2] = a2; shA[4*lane+3] = a3;
        shE[lane] = e;
    }
    __syncthreads();                               // one-time, post-loop
    if (lane == 0) {
        const int L  = label_len[b];
        const int s1 = 2*L - 1, s2 = 2*L;
        const float v1 = shA[s1], v2 = shA[s2];
        const int   e1 = shE[s1 >> 2], e2 = shE[s2 >> 2];
        const int   em = e1 > e2 ? e1 : e2;
        const float sum = ldexpf(v1, e1-em) + ldexpf(v2, e2-em);
        const float r   = __log2f(sum) + (float)em;
        out[b] = -LN2f * r;
    }
}

extern "C" void kernel_launch(void* const* d_in, const int* in_sizes, int n_in,
                              void* d_out, int out_size, void* d_ws, size_t ws_size,
                              hipStream_t stream) {
    const float* y_pred    = (const float*)d_in[0];
    const int*   y_true    = (const int*)d_in[1];
    const int*   label_len = (const int*)d_in[2];
    float*       out       = (float*)d_out;
    ctc_vg_kernel<<<Bc, 64, 0, stream>>>(y_pred, y_true, label_len, out);
}

// Round 8
// 258.081 us; speedup vs baseline: 1.0878x; 1.0878x over previous
//
#include <hip/hip_runtime.h>
#include <stdint.h>

// CTC batch cost, linear-domain, single wave per batch element, DIAGONAL SKEW.
// Lane L owns states 4L..4L+3 (S=201); at wave-step n it computes t = n-L.
// ROUND 8: r4 structure (proven absmax 0.0, fastest at 115us) with ALL loop
// memory ops in inline asm + hand-counted waitcnts. Tests the r7 theory
// (compiler emits conservative lgkm drains for cross-iteration DS values ->
// the ~150cy/step residual) with minimal new surface after r7's crash:
//   - NO global_load_lds builtin; staging = asm global_load_dwordx2 (vm) +
//     asm ds_write_b64, exactly r4's dataflow.
//   - LDS byte addresses from a proper generic->addrspace(3) cast.
//   - gathers issued 2 steps ahead into A/B parity register sets (j&1,
//     compile-time selected); halo/epoch via asm ds_bpermute (2-step slack,
//     r4's pipes and epoch tables verbatim).
// Wait accounting (in-order DS retirement within a wave):
//   body(n) issue order: W=ds_write(1), R=gathers(3), P=bperm(1; +1 e-bperm
//   on renorm steps). Consumed at body(n) top: R(n-2), P(n-2).
//   Newer ops = C(n-1) in {5,6}; s_waitcnt lgkmcnt(5) leaves at most the 5
//   newest outstanding >= subset of body(n-1)'s -> all of body(n-2) retired.
//   vmcnt: Q[qi] loaded at body(n-8); outstanding loads at body(n) = 7
//   (bodies n-7..n-1) -> s_waitcnt vmcnt(7) before the ds_write.
//   sched_barrier(0) after the lgkm wait (rule #18: VALU consumers must not
//   hoist above it). DS read-after-write needs no wait (in-order DS pipe);
//   row r is written at body(r-15), read at body(r-2+lane... ) >= 11 later.
// Ring safety / dormant lanes: identical to r4 (slots pre-zeroed; dormant
// reads see exact 0.0 or clamped finite rows, contributions 0*finite = 0;
// wrapped slot row n+2-lane+128 <= n+15 would need lane >= 115: never).
// EPS moved from staging to consume: same float ops on same values ->
// bit-identical. Epilogue drains vm+lgkm so pending asm writebacks can't
// corrupt reallocated VGPRs.

#define Bc 256
#define Tc 1024
#define Cc 128
#define Uc 100
#define BLANKc 127
#define EPSc 1e-7f
#define LN2f 0.69314718055994530942f
#define RSTRIDE 130            // floats per row slot (r4 layout, proven)
#define RSB (RSTRIDE*4)        // 520 bytes per row
#define NSLOT 128
#define SLOTB (NSLOT*RSB)      // 66560 bytes
#define QD 8

typedef __attribute__((address_space(3))) float LDSF;

#define DSREAD(dst, ad) \
    asm volatile("ds_read_b32 %0, %1" : "=v"(dst) : "v"(ad) : "memory")
#define DSWRITE64(ad, data) \
    asm volatile("ds_write_b64 %0, %1" :: "v"(ad), "v"(data) : "memory")
#define BPERM(dst, idx, src) \
    asm volatile("ds_bpermute_b32 %0, %1, %2" : "=v"(dst) : "v"(idx), "v"(src) : "memory")
#define GLOAD2(dst, ptr) \
    asm volatile("global_load_dwordx2 %0, %1, off" : "=v"(dst) : "v"(ptr) : "memory")

__global__ __launch_bounds__(64) void ctc_asm_kernel(
    const float* __restrict__ y_pred,     // [B,T,C] post-softmax probs
    const int*   __restrict__ y_true,     // [B,U]
    const int*   __restrict__ label_len,  // [B]
    float*       __restrict__ out)        // [B,1]
{
    __shared__ __align__(16) float rowbuf[NSLOT * RSTRIDE];
    __shared__ float shA[204];
    __shared__ int   shE[64];

    const int b    = blockIdx.x;
    const int lane = threadIdx.x;                  // 0..63
    const float* gp = y_pred + (size_t)b * (Tc * Cc);

    // ---- per-lane label classes & skip masks (time-invariant) ----
    const int k0  = 2*lane, k1 = 2*lane+1;
    const int k0c = k0 < Uc ? k0 : Uc-1;
    const int k1c = k1 < Uc ? k1 : Uc-1;
    const int y0  = y_true[b*Uc + k0c];            // class of state 4L+1
    const int y1  = y_true[b*Uc + k1c];            // class of state 4L+3
    int ym1 = y0;
    if (lane > 0) ym1 = y_true[b*Uc + k0 - 1];
    const float ms1 = (lane > 0 && y0 != ym1) ? 1.0f : 0.0f;
    const float ms3 = (y1 != y0) ? 1.0f : 0.0f;
    const float mh  = (lane > 0) ? 1.0f : 0.0f;    // lane 0 has no left halo
    const uint32_t y0B = (uint32_t)y0 << 2;        // class byte offsets
    const uint32_t y1B = (uint32_t)y1 << 2;
    const uint32_t BLB = (uint32_t)BLANKc << 2;
    const int lane2 = lane * 2;
    const uint32_t lane8 = (uint32_t)lane * 8u;

    // ---- t=0 init (only lane 0 holds mass) ----
    float a0=0.f, a1=0.f, a2=0.f, a3=0.f;
    if (lane == 0) { a0 = gp[BLANKc]+EPSc; a1 = gp[y0]+EPSc; }
    int e = 0;

    // ---- LDS byte base via proper generic->AS(3) cast ----
    const uint32_t rb0 = (uint32_t)(uintptr_t)(LDSF*)rowbuf;

    // ---- pre-zero ring (wrapped/dormant reads -> exact 0.0) ----
    {
        const float4 z = make_float4(0.f,0.f,0.f,0.f);
        float4* r4p = (float4*)rowbuf;             // 4160 float4 = 65*64
#pragma unroll
        for (int i = 0; i < 65; ++i) r4p[i*64 + lane] = z;
    }

    // ---- pre-stage rows 0..15 (coalesced float4, NO eps: eps at consume)
#pragma unroll
    for (int i = 0; i < 8; ++i) {
        const int f4  = i*64 + lane;               // 512 float4 across 16 rows
        const int row = f4 >> 5;                   // 32 float4 per row
        const int c4  = (f4 & 31) * 4;
        const float4 v = *(const float4*)(gp + row*Cc + c4);
        float* dst = &rowbuf[row*RSTRIDE + c4];
        dst[0]=v.x; dst[1]=v.y; dst[2]=v.z; dst[3]=v.w;
    }

    // ---- staging queue: rows 16..23 in flight (asm loads) ----
    uint64_t Q[QD];
#pragma unroll
    for (int k = 0; k < QD; ++k)
        GLOAD2(Q[k], gp + (16+k)*Cc + lane2);

    // ---- parity prob sets + halo/epoch pipes ----
    float pqbA, pq0A, pq1A, pqbB, pq0B, pq1B;
    float hqA = 0.f, hqB = 0.f;
    int   ELa = 0,  ELb = 0;
    const uint32_t up4 = (uint32_t)((lane > 0 ? lane-1 : 0) * 4);

    // prime gathers for steps 1 (A) and 2 (B); rows <= 2 prestaged/zeroed
    asm volatile("s_waitcnt lgkmcnt(0)" ::: "memory");   // prestage committed
    {
        const uint32_t s1 = rb0 + (((uint32_t)(1 - lane)) & 127u) * RSB;
        const uint32_t s2 = rb0 + (((uint32_t)(2 - lane)) & 127u) * RSB;
        DSREAD(pqbA, s1 + BLB); DSREAD(pq0A, s1 + y0B); DSREAD(pq1A, s1 + y1B);
        DSREAD(pqbB, s2 + BLB); DSREAD(pq0B, s2 + y0B); DSREAD(pq1B, s2 + y1B);
    }
    asm volatile("s_waitcnt vmcnt(0) lgkmcnt(0)" ::: "memory");
    __builtin_amdgcn_sched_barrier(0);

    // ---- incremental byte offsets (pre-increment form) ----
    int swb = (int)((((uint32_t)(3 - lane)) & 127u) * RSB) - RSB;  // gathers
    if (swb < 0) swb += SLOTB;                     // -> row n+2-lane at body n
    int wswb = 15 * RSB;                           // write: slot (n+15)&127

    auto body = [&](int n, int j, bool fzp) {
        // 1: counted lgkm wait + scheduling fence
        asm volatile("s_waitcnt lgkmcnt(5)" ::: "memory");
        __builtin_amdgcn_sched_barrier(0);
        const bool sA = ((j & 1) == 0);            // n odd <=> j even <=> A
        // 2: consume probs (gathered at n-2) + halo (bpermuted at n-2)
        const float pbr = sA ? pqbA : pqbB;
        const float p0r = sA ? pq0A : pq0B;
        const float p1r = sA ? pq1A : pq1B;
        const float h1r = sA ? hqA  : hqB;
        const int   el  = ((j == 0) || (j >= 5 && j <= 8) || (j >= 13)) ? ELb : ELa;
        const float pb = pbr + EPSc, p0 = p0r + EPSc, p1 = p1r + EPSc;
        int d = el - e; d = d > 126 ? 126 : d;
        const float h1 = mh * ldexpf(h1r, d);
        const float n0 = (a0 + h1) * pb;
        const float n1 = (a1 + a0 + ms1*h1) * p0;
        const float nv = (a2 + a1) * pb;
        const float n3 = (a3 + a2 + ms3*a1) * p1;
        bool upd = true;
        if (fzp) upd = (lane >= n - (Tc-1));       // freeze lanes past t=1023
        if (upd) { a0=n0; a1=n1; a2=nv; a3=n3; }
        if ((j & 3) == 3) {                        // renorm (pow2-exact)
            const float m = fmaxf(fmaxf(a0,a1), fmaxf(a2,a3));
            int ex = (int)((__float_as_uint(m) >> 23) & 0xFF) - 127;
            ex = (m > 0.0f) ? ex : (el - e);       // dormant: adopt left epoch
            a0 = ldexpf(a0,-ex); a1 = ldexpf(a1,-ex);
            a2 = ldexpf(a2,-ex); a3 = ldexpf(a3,-ex);
            e += ex;
        }
        // 3: stage row n+15 (Q loaded at n-8; vmcnt(7) retires it), reload
        wswb += RSB; if (wswb >= SLOTB) wswb -= SLOTB;
        asm volatile("s_waitcnt vmcnt(7)" ::: "memory");
        DSWRITE64(rb0 + (uint32_t)wswb + lane8, Q[j & 7]);
        int lr = n + 23; lr = lr > Tc-1 ? Tc-1 : lr;
        GLOAD2(Q[j & 7], gp + lr*Cc + lane2);
        // 4: gathers for step n+2 into this parity's (now-dead) regs
        swb += RSB; if (swb >= SLOTB) swb -= SLOTB;
        const uint32_t ga = rb0 + (uint32_t)swb;
        if (sA) { DSREAD(pqbA, ga + BLB); DSREAD(pq0A, ga + y0B); DSREAD(pq1A, ga + y1B); }
        else    { DSREAD(pqbB, ga + BLB); DSREAD(pq0B, ga + y0B); DSREAD(pq1B, ga + y1B); }
        // 5: halo a3 (post-renorm on renorm steps); e once per renorm
        if (sA) { BPERM(hqA, up4, a3); } else { BPERM(hqB, up4, a3); }
        if ((j & 3) == 3) {
            if (j == 3 || j == 11) { BPERM(ELb, up4, e); }
            else                   { BPERM(ELa, up4, e); }
        }
    };

    // ---- wave-steps n = 1..1073 (lane 50 ends t=1023 at n=1073) ----
    int n = 1;
    for (int c = 0; c < 63; ++c) {                 // n = 1..1008: no freeze
#pragma unroll
        for (int j = 0; j < 16; ++j) { body(n, j, false); ++n; }
    }
    for (int c = 0; c < 4; ++c) {                  // n = 1009..1072 (freeze
#pragma unroll                                     //  predicate inert <1024)
        for (int j = 0; j < 16; ++j) { body(n, j, true); ++n; }
    }
    body(n, 0, true);                              // n = 1073 ((1073-1)&15==0)

    // drain: no pending asm writeback may land in reallocated VGPRs
    asm volatile("s_waitcnt vmcnt(0) lgkmcnt(0)" ::: "memory");
    __builtin_amdgcn_sched_barrier(0);

    // ---- epilogue: loss = -ln( A[2L-1] + A[2L] ), A = a * 2^e ----
    if (lane < 51) {
        shA[4*lane+0] = a0; shA[4*lane+1] = a1;
        shA[4*lane+2] = a2; shA[4*lane+3] = a3;
        shE[lane] = e;
    }
    __syncthreads();                               // one-time, post-loop
    if (lane == 0) {
        const int L  = label_len[b];
        const int s1 = 2*L - 1, s2 = 2*L;
        const float v1 = shA[s1], v2 = shA[s2];
        const int   e1 = shE[s1 >> 2], e2 = shE[s2 >> 2];
        const int   em = e1 > e2 ? e1 : e2;
        const float sum = ldexpf(v1, e1-em) + ldexpf(v2, e2-em);
        const float r   = __log2f(sum) + (float)em;
        out[b] = -LN2f * r;
    }
}

extern "C" void kernel_launch(void* const* d_in, const int* in_sizes, int n_in,
                              void* d_out, int out_size, void* d_ws, size_t ws_size,
                              hipStream_t stream) {
    const float* y_pred    = (const float*)d_in[0];
    const int*   y_true    = (const int*)d_in[1];
    const int*   label_len = (const int*)d_in[2];
    float*       out       = (float*)d_out;
    ctc_asm_kernel<<<Bc, 64, 0, stream>>>(y_pred, y_true, label_len, out);
}